// Round 6
// baseline (1069.524 us; speedup 1.0000x reference)
//
#include <hip/hip_runtime.h>
#include <hip/hip_bf16.h>
#include <cmath>

constexpr int kCIN = 128, kHID = 256, kOUT = 349;
constexpr int kNT = 4, kET = 5;
constexpr int kN0 = 120000, kN1 = 40000, kN2 = 10000;
constexpr int kNSEG0 = kN1 * kET;   // 200000
constexpr int kNSEG1 = kN2 * kET;   // 50000
constexpr int kNSEG = kNSEG0 + kNSEG1;  // 250000

constexpr int kBinSegs = 512;                               // segments per bin
constexpr int kBinCap  = 8192;                              // max edges per bin (stat max ~4100)
constexpr int kNBin0 = (kNSEG0 + kBinSegs - 1) / kBinSegs;  // 391
constexpr int kNBin1 = (kNSEG1 + kBinSegs - 1) / kBinSegs;  // 98
constexpr int kNBin  = kNBin0 + kNBin1;                     // 489

typedef __bf16 bf16x8 __attribute__((ext_vector_type(8)));
typedef float f32x4 __attribute__((ext_vector_type(4)));
typedef unsigned short ushort8v __attribute__((ext_vector_type(8)));

__device__ __forceinline__ unsigned short f2b(float f) {
    unsigned int b = __float_as_uint(f);
    unsigned int r = (b + 0x7FFFu + ((b >> 16) & 1u)) >> 16;
    return (unsigned short)r;
}
__device__ __forceinline__ float b2f(unsigned short u) {
    return __uint_as_float((unsigned int)u << 16);
}

// ---------------- input gather: h0[i] = bf16(table[nt][min(li, rows-1)]) ----
__global__ void k_gather(const int* __restrict__ n_id, const float* __restrict__ x0,
                         const float* __restrict__ e1, const float* __restrict__ e2,
                         const float* __restrict__ e3, const int* __restrict__ ntype,
                         const int* __restrict__ lidx, unsigned short* __restrict__ h0b,
                         int* __restrict__ nt0)
{
    int row = blockIdx.x * 8 + (threadIdx.x >> 5);
    if (row >= kN0) return;
    int lane = threadIdx.x & 31;
    int gid = n_id[row];
    int nt = ntype[gid];
    int li = lidx[gid];
    const float* tab;
    int rows;
    if (nt == 0)      { tab = x0; rows = 100000; }
    else if (nt == 1) { tab = e1; rows = 50000; }
    else if (nt == 2) { tab = e2; rows = 50000; }
    else              { tab = e3; rows = 50000; }
    int idx = li < rows ? li : rows - 1;
    float4 v = reinterpret_cast<const float4*>(tab + (size_t)idx * kCIN)[lane];
    ushort4 o;
    o.x = f2b(v.x); o.y = f2b(v.y); o.z = f2b(v.z); o.w = f2b(v.w);
    reinterpret_cast<ushort4*>(h0b + (size_t)row * kCIN)[lane] = o;
    if (lane == 0) nt0[row] = nt;
}

// ---------------- binned partition: edge -> (bin, src|segloc<<17) -----------
__global__ void k_binpart(const int* __restrict__ src0, const int* __restrict__ dst0,
                          const int* __restrict__ eid0, int E0,
                          const int* __restrict__ src1, const int* __restrict__ dst1,
                          const int* __restrict__ eid1, int E1,
                          const int* __restrict__ etype,
                          int* __restrict__ bincur, unsigned int* __restrict__ pairs)
{
    int i = blockIdx.x * 256 + threadIdx.x;
    int bin; unsigned int pay;
    if (i < E0) {
        int seg = dst0[i] * kET + etype[eid0[i]];
        bin = seg >> 9;
        pay = (unsigned int)src0[i] | ((unsigned int)(seg & (kBinSegs - 1)) << 17);
    } else if (i < E0 + E1) {
        int e = i - E0;
        int seg = dst1[e] * kET + etype[eid1[e]];
        bin = kNBin0 + (seg >> 9);
        pay = (unsigned int)src1[e] | ((unsigned int)(seg & (kBinSegs - 1)) << 17);
    } else return;
    int p = atomicAdd(&bincur[bin], 1);
    if (p < kBinCap) pairs[(size_t)bin * kBinCap + p] = pay;
}

// ---------------- per-bin: LDS hist + scan -> starts/cnt, LDS-cursor scatter -
__global__ __launch_bounds__(1024) void k_binscatter(
    const int* __restrict__ bincur, const unsigned int* __restrict__ pairs,
    int* __restrict__ order, int* __restrict__ starts, int* __restrict__ cnt)
{
    __shared__ int h[kBinSegs];
    __shared__ int sc[kBinSegs];
    __shared__ int cur[kBinSegs];
    const int bin = blockIdx.x;
    const int tid = threadIdx.x;
    int c = bincur[bin];
    if (c > kBinCap) c = kBinCap;
    const unsigned int* pp = pairs + (size_t)bin * kBinCap;

    for (int k = tid; k < kBinSegs; k += 1024) h[k] = 0;
    __syncthreads();
    for (int j = tid; j < c; j += 1024) atomicAdd(&h[pp[j] >> 17], 1);
    __syncthreads();
    if (tid < kBinSegs) sc[tid] = h[tid];
    __syncthreads();
    for (int off = 1; off < kBinSegs; off <<= 1) {
        int t = 0;
        if (tid < kBinSegs && tid >= off) t = sc[tid - off];
        __syncthreads();
        if (tid < kBinSegs) sc[tid] += t;
        __syncthreads();
    }
    int seg_rel, abs_base, seglim;
    if (bin < kNBin0) { seg_rel = bin * kBinSegs; abs_base = seg_rel; seglim = kNSEG0 - seg_rel; }
    else { seg_rel = (bin - kNBin0) * kBinSegs; abs_base = kNSEG0 + seg_rel; seglim = kNSEG1 - seg_rel; }
    if (tid < kBinSegs) {
        int excl = sc[tid] - h[tid];
        cur[tid] = excl;
        if (tid < seglim) {
            starts[abs_base + tid] = bin * kBinCap + excl;
            cnt[abs_base + tid] = h[tid];
        }
    }
    __syncthreads();
    for (int j = tid; j < c; j += 1024) {
        unsigned int u = pp[j];
        int sl = (int)(u >> 17);
        int p = atomicAdd(&cur[sl], 1);
        order[(size_t)bin * kBinCap + p] = (int)(u & 0x1FFFFu);
    }
}

// ---------------- per-segment gather-mean (bf16 in/out, f32 acc) ------------
template<int C>
__global__ __launch_bounds__(256) void k_segreduce(
    const int* __restrict__ starts, const int* __restrict__ cnt,
    const int* __restrict__ order, const unsigned short* __restrict__ h,
    unsigned short* __restrict__ mean, int nseg)
{
    constexpr int L = C / 8;          // lanes per segment (8 bf16 = 16B each)
    constexpr int SPB = 256 / L;
    int sidx = blockIdx.x * SPB + threadIdx.x / L;
    if (sidx >= nseg) return;
    int lane = threadIdx.x % L;
    int st = starts[sidx];
    int n = cnt[sidx];
    const unsigned short* hp = h + (size_t)lane * 8;
    float a0[8] = {0.f, 0.f, 0.f, 0.f, 0.f, 0.f, 0.f, 0.f};
    float a1[8] = {0.f, 0.f, 0.f, 0.f, 0.f, 0.f, 0.f, 0.f};
    int j = 0;
    for (; j + 2 <= n; j += 2) {
        int s0 = order[st + j];
        int s1 = order[st + j + 1];
        ushort8v v0 = *reinterpret_cast<const ushort8v*>(hp + (size_t)s0 * C);
        ushort8v v1 = *reinterpret_cast<const ushort8v*>(hp + (size_t)s1 * C);
#pragma unroll
        for (int i = 0; i < 8; i++) { a0[i] += b2f(v0[i]); a1[i] += b2f(v1[i]); }
    }
    if (j < n) {
        int s0 = order[st + j];
        ushort8v v0 = *reinterpret_cast<const ushort8v*>(hp + (size_t)s0 * C);
#pragma unroll
        for (int i = 0; i < 8; i++) a0[i] += b2f(v0[i]);
    }
    float sc = 1.0f / fmaxf((float)n, 1.0f);
    ushort8v o;
#pragma unroll
    for (int i = 0; i < 8; i++) o[i] = f2b((a0[i] + a1[i]) * sc);
    *reinterpret_cast<ushort8v*>(mean + (size_t)sidx * C + lane * 8) = o;
}

// ---------------- weight prep: Bt[col][k] = bf16([relW;rootW][k][col]) ------
__global__ void k_prepw(const float* __restrict__ relW, const float* __restrict__ rootW,
                        unsigned short* __restrict__ Bt, int N, int Npad, int K1, int K)
{
    int i = blockIdx.x * 256 + threadIdx.x;
    if (i >= Npad * K) return;
    int col = i / K;
    int k = i - col * K;
    float v = 0.f;
    if (col < N) v = (k < K1) ? relW[(size_t)k * N + col] : rootW[(size_t)(k - K1) * N + col];
    Bt[i] = f2b(v);
}

// ---------------- MFMA GEMM: out = [mean | onehot(nt)*h] @ Bt^T + rootb[nt] -
// Templated tile BM x BN (BM,BN in {64,128}), 4 waves as 2x2, BK=64.
template<int C, int BM, int BN, int RELU, int OUTBF16>
__global__ __launch_bounds__(256) void k_gemm_mfma(
    int M, int Nreal,
    const unsigned short* __restrict__ meanb,
    const unsigned short* __restrict__ hb,
    const unsigned short* __restrict__ Bt,
    const float* __restrict__ rootb,
    const int* __restrict__ nt0,
    unsigned short* __restrict__ outb, float* __restrict__ outf)
{
    constexpr int K1 = kET * C;
    constexpr int K = K1 + kNT * C;
    constexpr int LOG2C = (C == 128) ? 7 : 8;
    constexpr int FM = BM / 32;   // 16x16 frags per wave (M)
    constexpr int FN = BN / 32;   // 16x16 frags per wave (N)
    __shared__ __align__(16) char ldsA[BM * 128];
    __shared__ __align__(16) char ldsB[BN * 128];

    const int tid = threadIdx.x;
    const int row0 = blockIdx.x * BM;
    const int col0 = blockIdx.y * BN;
    const int wid = tid >> 6, lane = tid & 63;
    const int wrow = (wid >> 1) * (BM / 2);
    const int wcol = (wid & 1) * (BN / 2);
    const int sr = tid >> 3;            // staging row 0..31 (+p*32)
    const int skb = (tid & 7) * 16;     // staging byte offset in 128B row

    f32x4 acc[FM][FN] = {};

    for (int k0 = 0; k0 < K; k0 += 64) {
        int kg = k0 + (skb >> 1);
#pragma unroll
        for (int p = 0; p < BM / 32; p++) {
            int r = sr + p * 32;
            int row = row0 + r;
            ushort8v va = {0, 0, 0, 0, 0, 0, 0, 0};
            if (row < M) {
                if (kg < K1) {
                    va = *reinterpret_cast<const ushort8v*>(meanb + (size_t)row * K1 + kg);
                } else {
                    int kr = kg - K1;
                    if (nt0[row] == (kr >> LOG2C))
                        va = *reinterpret_cast<const ushort8v*>(hb + (size_t)row * C + (kr & (C - 1)));
                }
            }
            *reinterpret_cast<ushort8v*>(&ldsA[r * 128 + (skb ^ ((r & 7) << 4))]) = va;
        }
#pragma unroll
        for (int p = 0; p < BN / 32; p++) {
            int r = sr + p * 32;
            int colr = col0 + r;
            ushort8v vb = *reinterpret_cast<const ushort8v*>(Bt + (size_t)colr * K + kg);
            *reinterpret_cast<ushort8v*>(&ldsB[r * 128 + (skb ^ ((r & 7) << 4))]) = vb;
        }
        __syncthreads();
#pragma unroll
        for (int kc = 0; kc < 2; kc++) {
            int kb = kc * 64 + (lane >> 4) * 16;
            bf16x8 af[FM], bfr[FN];
#pragma unroll
            for (int m = 0; m < FM; m++) {
                int r = wrow + m * 16 + (lane & 15);
                af[m] = *reinterpret_cast<const bf16x8*>(&ldsA[r * 128 + (kb ^ ((r & 7) << 4))]);
            }
#pragma unroll
            for (int n = 0; n < FN; n++) {
                int r = wcol + n * 16 + (lane & 15);
                bfr[n] = *reinterpret_cast<const bf16x8*>(&ldsB[r * 128 + (kb ^ ((r & 7) << 4))]);
            }
#pragma unroll
            for (int m = 0; m < FM; m++)
#pragma unroll
                for (int n = 0; n < FN; n++)
                    acc[m][n] = __builtin_amdgcn_mfma_f32_16x16x32_bf16(af[m], bfr[n], acc[m][n], 0, 0, 0);
        }
        __syncthreads();
    }

    // epilogue: C/D mapping col=lane&15, row=(lane>>4)*4+j
#pragma unroll
    for (int m = 0; m < FM; m++) {
        int rbase = row0 + wrow + m * 16 + (lane >> 4) * 4;
#pragma unroll
        for (int n = 0; n < FN; n++) {
            int col = col0 + wcol + n * 16 + (lane & 15);
            if (col >= Nreal) continue;
            f32x4 v = acc[m][n];
#pragma unroll
            for (int j = 0; j < 4; j++) {
                int row = rbase + j;
                if (row >= M) continue;
                float x = v[j] + rootb[nt0[row] * Nreal + col];
                if (RELU) x = fmaxf(x, 0.f);
                if (OUTBF16) outb[(size_t)row * Nreal + col] = f2b(x);
                else         outf[(size_t)row * Nreal + col] = x;
            }
        }
    }
}

// ---------------- in-place log_softmax over rows of N cols ------------------
__global__ void k_logsm(float* __restrict__ out, int M, int N)
{
    int row = blockIdx.x * 4 + (threadIdx.x >> 6);
    if (row >= M) return;
    int lane = threadIdx.x & 63;
    float* p = out + (size_t)row * N;
    float mx = -3.4e38f;
    for (int c = lane; c < N; c += 64) mx = fmaxf(mx, p[c]);
#pragma unroll
    for (int o = 32; o > 0; o >>= 1) mx = fmaxf(mx, __shfl_xor(mx, o));
    float s = 0.f;
    for (int c = lane; c < N; c += 64) s += expf(p[c] - mx);
#pragma unroll
    for (int o = 32; o > 0; o >>= 1) s += __shfl_xor(s, o);
    float lse = mx + logf(s);
    for (int c = lane; c < N; c += 64) p[c] -= lse;
}

extern "C" void kernel_launch(void* const* d_in, const int* in_sizes, int n_in,
                              void* d_out, int out_size, void* d_ws, size_t ws_size,
                              hipStream_t stream)
{
    const int*   n_id   = (const int*)d_in[0];
    const float* x0     = (const float*)d_in[1];
    const int*   src0   = (const int*)d_in[2];
    const int*   dst0   = (const int*)d_in[3];
    const int*   eid0   = (const int*)d_in[4];
    const int*   src1   = (const int*)d_in[5];
    const int*   dst1   = (const int*)d_in[6];
    const int*   eid1   = (const int*)d_in[7];
    const int*   etype  = (const int*)d_in[8];
    const int*   ntype  = (const int*)d_in[9];
    const int*   lidx   = (const int*)d_in[10];
    const float* emb1   = (const float*)d_in[11];
    const float* emb2   = (const float*)d_in[12];
    const float* emb3   = (const float*)d_in[13];
    const float* relW0  = (const float*)d_in[14];
    const float* rootW0 = (const float*)d_in[15];
    const float* rootb0 = (const float*)d_in[16];
    const float* relW1  = (const float*)d_in[17];
    const float* rootW1 = (const float*)d_in[18];
    const float* rootb1 = (const float*)d_in[19];
    float* out = (float*)d_out;

    const int E0 = in_sizes[2];
    const int E1 = in_sizes[5];
    constexpr int K0 = kET * kCIN + kNT * kCIN;   // 1152
    constexpr int Kb1 = kET * kHID + kNT * kHID;  // 2304
    constexpr int Npad1 = 384;

    char* ws = (char*)d_ws;
    size_t off = 0;
    auto alloc = [&](size_t bytes) -> void* {
        void* p = ws + off;
        off = (off + bytes + 255) & ~(size_t)255;
        return p;
    };
    unsigned short* h0b   = (unsigned short*)alloc((size_t)kN0 * kCIN * 2);
    int*            nt0   = (int*)alloc((size_t)kN0 * 4);
    unsigned short* meanb = (unsigned short*)alloc((size_t)kNSEG0 * kCIN * 2); // >= NSEG1*HID
    int*            cnt    = (int*)alloc((size_t)kNSEG * 4);
    int*            starts = (int*)alloc((size_t)kNSEG * 4);
    int*            bincur = (int*)alloc((size_t)kNBin * 4);
    unsigned int*   pairs  = (unsigned int*)alloc((size_t)kNBin * kBinCap * 4);  // 16 MB
    int*            order  = (int*)alloc((size_t)kNBin * kBinCap * 4);           // 16 MB
    unsigned short* h1b   = (unsigned short*)alloc((size_t)kN1 * kHID * 2);
    unsigned short* Bt0   = (unsigned short*)alloc((size_t)kHID * K0 * 2);
    unsigned short* Bt1   = (unsigned short*)alloc((size_t)Npad1 * Kb1 * 2);

    // ---- weight prep + input gather (independent of CSR build) ----
    k_prepw<<<(kHID * K0 + 255) / 256, 256, 0, stream>>>(relW0, rootW0, Bt0, kHID, kHID, kET * kCIN, K0);
    k_prepw<<<(Npad1 * Kb1 + 255) / 256, 256, 0, stream>>>(relW1, rootW1, Bt1, kOUT, Npad1, kET * kHID, Kb1);
    k_gather<<<(kN0 + 7) / 8, 256, 0, stream>>>(n_id, x0, emb1, emb2, emb3, ntype, lidx, h0b, nt0);

    // ---- binned CSR build (both layers) ----
    hipMemsetAsync(bincur, 0, (size_t)kNBin * 4, stream);
    int Etot = E0 + E1;
    k_binpart<<<(Etot + 255) / 256, 256, 0, stream>>>(src0, dst0, eid0, E0, src1, dst1, eid1, E1,
                                                      etype, bincur, pairs);
    k_binscatter<<<kNBin, 1024, 0, stream>>>(bincur, pairs, order, starts, cnt);

    // ---- layer 0 ----
    k_segreduce<kCIN><<<(kNSEG0 + 15) / 16, 256, 0, stream>>>(starts, cnt, order, h0b, meanb, kNSEG0);
    dim3 g0((kN1 + 63) / 64, kHID / 128);
    k_gemm_mfma<kCIN, 64, 128, 1, 1><<<g0, 256, 0, stream>>>(kN1, kHID, meanb, h0b, Bt0, rootb0, nt0, h1b, nullptr);

    // ---- layer 1 ----
    k_segreduce<kHID><<<(kNSEG1 + 7) / 8, 256, 0, stream>>>(starts + kNSEG0, cnt + kNSEG0, order, h1b, meanb, kNSEG1);
    dim3 g1((kN2 + 63) / 64, Npad1 / 64);
    k_gemm_mfma<kHID, 64, 64, 0, 0><<<g1, 256, 0, stream>>>(kN2, kOUT, meanb, h1b, Bt1, rootb1, nt0, nullptr, out);

    k_logsm<<<(kN2 + 3) / 4, 256, 0, stream>>>(out, kN2, kOUT);
}

// Round 7
// 342.718 us; speedup vs baseline: 3.1207x; 3.1207x over previous
//
#include <hip/hip_runtime.h>
#include <hip/hip_bf16.h>
#include <cmath>

constexpr int kCIN = 128, kHID = 256, kOUT = 349;
constexpr int kNT = 4, kET = 5;
constexpr int kN0 = 120000, kN1 = 40000, kN2 = 10000;
constexpr int kNSEG0 = kN1 * kET;   // 200000
constexpr int kNSEG1 = kN2 * kET;   // 50000
constexpr int kNSEG = kNSEG0 + kNSEG1;  // 250000

constexpr int kBinSegs = 512;                               // segments per bin
constexpr int kNBin0 = (kNSEG0 + kBinSegs - 1) / kBinSegs;  // 391
constexpr int kNBin1 = (kNSEG1 + kBinSegs - 1) / kBinSegs;  // 98
constexpr int kNBin  = kNBin0 + kNBin1;                     // 489
constexpr int kNBLK  = 512;                                 // partition blocks

typedef __bf16 bf16x8 __attribute__((ext_vector_type(8)));
typedef float f32x4 __attribute__((ext_vector_type(4)));
typedef unsigned short ushort8v __attribute__((ext_vector_type(8)));

__device__ __forceinline__ unsigned short f2b(float f) {
    unsigned int b = __float_as_uint(f);
    unsigned int r = (b + 0x7FFFu + ((b >> 16) & 1u)) >> 16;
    return (unsigned short)r;
}
__device__ __forceinline__ float b2f(unsigned short u) {
    return __uint_as_float((unsigned int)u << 16);
}

// ---------------- input gather: h0[i] = bf16(table[nt][min(li, rows-1)]) ----
__global__ void k_gather(const int* __restrict__ n_id, const float* __restrict__ x0,
                         const float* __restrict__ e1, const float* __restrict__ e2,
                         const float* __restrict__ e3, const int* __restrict__ ntype,
                         const int* __restrict__ lidx, unsigned short* __restrict__ h0b,
                         int* __restrict__ nt0)
{
    int row = blockIdx.x * 8 + (threadIdx.x >> 5);
    if (row >= kN0) return;
    int lane = threadIdx.x & 31;
    int gid = n_id[row];
    int nt = ntype[gid];
    int li = lidx[gid];
    const float* tab;
    int rows;
    if (nt == 0)      { tab = x0; rows = 100000; }
    else if (nt == 1) { tab = e1; rows = 50000; }
    else if (nt == 2) { tab = e2; rows = 50000; }
    else              { tab = e3; rows = 50000; }
    int idx = li < rows ? li : rows - 1;
    float4 v = reinterpret_cast<const float4*>(tab + (size_t)idx * kCIN)[lane];
    ushort4 o;
    o.x = f2b(v.x); o.y = f2b(v.y); o.z = f2b(v.z); o.w = f2b(v.w);
    reinterpret_cast<ushort4*>(h0b + (size_t)row * kCIN)[lane] = o;
    if (lane == 0) nt0[row] = nt;
}

// ---------------- pass A: per-(block,bin) histogram (LDS, no global atomics) -
__global__ __launch_bounds__(1024) void k_bincnt(
    const int* __restrict__ dst0, const int* __restrict__ eid0, int E0,
    const int* __restrict__ dst1, const int* __restrict__ eid1, int E1,
    const int* __restrict__ etype, int* __restrict__ cnts2d)
{
    __shared__ int h[kNBin];
    const int tid = threadIdx.x;
    for (int k = tid; k < kNBin; k += 1024) h[k] = 0;
    __syncthreads();
    int Etot = E0 + E1;
    int chunk = (Etot + kNBLK - 1) / kNBLK;
    int lo = blockIdx.x * chunk;
    int hi = min(lo + chunk, Etot);
    for (int i = lo + tid; i < hi; i += 1024) {
        int bin;
        if (i < E0) bin = (dst0[i] * kET + etype[eid0[i]]) >> 9;
        else { int e = i - E0; bin = kNBin0 + ((dst1[e] * kET + etype[eid1[e]]) >> 9); }
        atomicAdd(&h[bin], 1);   // LDS atomic
    }
    __syncthreads();
    for (int k = tid; k < kNBin; k += 1024) cnts2d[(size_t)k * kNBLK + blockIdx.x] = h[k];
}

// ---------------- scans (exclusive, over kNBin*kNBLK elements) --------------
__global__ void k_scan1(const int* __restrict__ cnt, int* __restrict__ excl,
                        int* __restrict__ blksum, int n)
{
    __shared__ int sm[1024];
    int i = blockIdx.x * 1024 + threadIdx.x;
    int v = (i < n) ? cnt[i] : 0;
    sm[threadIdx.x] = v;
    __syncthreads();
    for (int off = 1; off < 1024; off <<= 1) {
        int t = (threadIdx.x >= off) ? sm[threadIdx.x - off] : 0;
        __syncthreads();
        sm[threadIdx.x] += t;
        __syncthreads();
    }
    if (i < n) excl[i] = sm[threadIdx.x] - v;
    if (threadIdx.x == 1023) blksum[blockIdx.x] = sm[1023];
}

__global__ void k_scan2(int* __restrict__ blksum, int nblk)
{
    __shared__ int sm[1024];
    int v = (threadIdx.x < nblk) ? blksum[threadIdx.x] : 0;
    sm[threadIdx.x] = v;
    __syncthreads();
    for (int off = 1; off < 1024; off <<= 1) {
        int t = (threadIdx.x >= off) ? sm[threadIdx.x - off] : 0;
        __syncthreads();
        sm[threadIdx.x] += t;
        __syncthreads();
    }
    if (threadIdx.x < nblk) blksum[threadIdx.x] = sm[threadIdx.x] - v;
}

__global__ void k_scan3(int* __restrict__ excl, const int* __restrict__ blksum, int n)
{
    int i = blockIdx.x * 256 + threadIdx.x;
    if (i < n) excl[i] += blksum[i >> 10];
}

// ---------------- pass B: place edges via LDS cursors (no global atomics) ---
__global__ __launch_bounds__(1024) void k_binplace(
    const int* __restrict__ src0, const int* __restrict__ dst0,
    const int* __restrict__ eid0, int E0,
    const int* __restrict__ src1, const int* __restrict__ dst1,
    const int* __restrict__ eid1, int E1,
    const int* __restrict__ etype, const int* __restrict__ offs2d,
    unsigned int* __restrict__ pairs)
{
    __shared__ int cur[kNBin];
    const int tid = threadIdx.x;
    for (int k = tid; k < kNBin; k += 1024) cur[k] = offs2d[(size_t)k * kNBLK + blockIdx.x];
    __syncthreads();
    int Etot = E0 + E1;
    int chunk = (Etot + kNBLK - 1) / kNBLK;
    int lo = blockIdx.x * chunk;
    int hi = min(lo + chunk, Etot);
    for (int i = lo + tid; i < hi; i += 1024) {
        int bin; unsigned int pay;
        if (i < E0) {
            int seg = dst0[i] * kET + etype[eid0[i]];
            bin = seg >> 9;
            pay = (unsigned int)src0[i] | ((unsigned int)(seg & (kBinSegs - 1)) << 17);
        } else {
            int e = i - E0;
            int seg = dst1[e] * kET + etype[eid1[e]];
            bin = kNBin0 + (seg >> 9);
            pay = (unsigned int)src1[e] | ((unsigned int)(seg & (kBinSegs - 1)) << 17);
        }
        int p = atomicAdd(&cur[bin], 1);   // LDS atomic
        pairs[p] = pay;
    }
}

// ---------------- per-bin: LDS hist + scan -> starts/cnt, LDS-cursor scatter -
__global__ __launch_bounds__(1024) void k_binscatter(
    const int* __restrict__ offs2d, int Etot, const unsigned int* __restrict__ pairs,
    int* __restrict__ order, int* __restrict__ starts, int* __restrict__ cnt)
{
    __shared__ int h[kBinSegs];
    __shared__ int sc[kBinSegs];
    __shared__ int cur[kBinSegs];
    const int bin = blockIdx.x;
    const int tid = threadIdx.x;
    const int base = offs2d[(size_t)bin * kNBLK];
    const int end  = (bin + 1 < kNBin) ? offs2d[(size_t)(bin + 1) * kNBLK] : Etot;
    const int c = end - base;
    const unsigned int* pp = pairs + base;

    for (int k = tid; k < kBinSegs; k += 1024) h[k] = 0;
    __syncthreads();
    for (int j = tid; j < c; j += 1024) atomicAdd(&h[pp[j] >> 17], 1);
    __syncthreads();
    if (tid < kBinSegs) sc[tid] = h[tid];
    __syncthreads();
    for (int off = 1; off < kBinSegs; off <<= 1) {
        int t = 0;
        if (tid < kBinSegs && tid >= off) t = sc[tid - off];
        __syncthreads();
        if (tid < kBinSegs) sc[tid] += t;
        __syncthreads();
    }
    int seg_rel, abs_base, seglim;
    if (bin < kNBin0) { seg_rel = bin * kBinSegs; abs_base = seg_rel; seglim = kNSEG0 - seg_rel; }
    else { seg_rel = (bin - kNBin0) * kBinSegs; abs_base = kNSEG0 + seg_rel; seglim = kNSEG1 - seg_rel; }
    if (tid < kBinSegs) {
        int excl = sc[tid] - h[tid];
        cur[tid] = excl;
        if (tid < seglim) {
            starts[abs_base + tid] = base + excl;
            cnt[abs_base + tid] = h[tid];
        }
    }
    __syncthreads();
    for (int j = tid; j < c; j += 1024) {
        unsigned int u = pp[j];
        int sl = (int)(u >> 17);
        int p = atomicAdd(&cur[sl], 1);
        order[base + p] = (int)(u & 0x1FFFFu);
    }
}

// ---------------- per-segment gather-mean (bf16 in/out, f32 acc) ------------
template<int C>
__global__ __launch_bounds__(256) void k_segreduce(
    const int* __restrict__ starts, const int* __restrict__ cnt,
    const int* __restrict__ order, const unsigned short* __restrict__ h,
    unsigned short* __restrict__ mean, int nseg)
{
    constexpr int L = C / 8;          // lanes per segment (8 bf16 = 16B each)
    constexpr int SPB = 256 / L;
    int sidx = blockIdx.x * SPB + threadIdx.x / L;
    if (sidx >= nseg) return;
    int lane = threadIdx.x % L;
    int st = starts[sidx];
    int n = cnt[sidx];
    const unsigned short* hp = h + (size_t)lane * 8;
    float a0[8] = {0.f, 0.f, 0.f, 0.f, 0.f, 0.f, 0.f, 0.f};
    float a1[8] = {0.f, 0.f, 0.f, 0.f, 0.f, 0.f, 0.f, 0.f};
    int j = 0;
    for (; j + 2 <= n; j += 2) {
        int s0 = order[st + j];
        int s1 = order[st + j + 1];
        ushort8v v0 = *reinterpret_cast<const ushort8v*>(hp + (size_t)s0 * C);
        ushort8v v1 = *reinterpret_cast<const ushort8v*>(hp + (size_t)s1 * C);
#pragma unroll
        for (int i = 0; i < 8; i++) { a0[i] += b2f(v0[i]); a1[i] += b2f(v1[i]); }
    }
    if (j < n) {
        int s0 = order[st + j];
        ushort8v v0 = *reinterpret_cast<const ushort8v*>(hp + (size_t)s0 * C);
#pragma unroll
        for (int i = 0; i < 8; i++) a0[i] += b2f(v0[i]);
    }
    float sc = 1.0f / fmaxf((float)n, 1.0f);
    ushort8v o;
#pragma unroll
    for (int i = 0; i < 8; i++) o[i] = f2b((a0[i] + a1[i]) * sc);
    *reinterpret_cast<ushort8v*>(mean + (size_t)sidx * C + lane * 8) = o;
}

// ---------------- weight prep: Bt[col][k] = bf16([relW;rootW][k][col]) ------
__global__ void k_prepw(const float* __restrict__ relW, const float* __restrict__ rootW,
                        unsigned short* __restrict__ Bt, int N, int Npad, int K1, int K)
{
    int i = blockIdx.x * 256 + threadIdx.x;
    if (i >= Npad * K) return;
    int col = i / K;
    int k = i - col * K;
    float v = 0.f;
    if (col < N) v = (k < K1) ? relW[(size_t)k * N + col] : rootW[(size_t)(k - K1) * N + col];
    Bt[i] = f2b(v);
}

// ---------------- MFMA GEMM: out = [mean | onehot(nt)*h] @ Bt^T + rootb[nt] -
template<int C, int BM, int BN, int RELU, int OUTBF16>
__global__ __launch_bounds__(256) void k_gemm_mfma(
    int M, int Nreal,
    const unsigned short* __restrict__ meanb,
    const unsigned short* __restrict__ hb,
    const unsigned short* __restrict__ Bt,
    const float* __restrict__ rootb,
    const int* __restrict__ nt0,
    unsigned short* __restrict__ outb, float* __restrict__ outf)
{
    constexpr int K1 = kET * C;
    constexpr int K = K1 + kNT * C;
    constexpr int LOG2C = (C == 128) ? 7 : 8;
    constexpr int FM = BM / 32;   // 16x16 frags per wave (M)
    constexpr int FN = BN / 32;   // 16x16 frags per wave (N)
    __shared__ __align__(16) char ldsA[BM * 128];
    __shared__ __align__(16) char ldsB[BN * 128];

    const int tid = threadIdx.x;
    const int row0 = blockIdx.x * BM;
    const int col0 = blockIdx.y * BN;
    const int wid = tid >> 6, lane = tid & 63;
    const int wrow = (wid >> 1) * (BM / 2);
    const int wcol = (wid & 1) * (BN / 2);
    const int sr = tid >> 3;            // staging row 0..31 (+p*32)
    const int skb = (tid & 7) * 16;     // staging byte offset in 128B row

    f32x4 acc[FM][FN] = {};

    for (int k0 = 0; k0 < K; k0 += 64) {
        int kg = k0 + (skb >> 1);
#pragma unroll
        for (int p = 0; p < BM / 32; p++) {
            int r = sr + p * 32;
            int row = row0 + r;
            ushort8v va = {0, 0, 0, 0, 0, 0, 0, 0};
            if (row < M) {
                if (kg < K1) {
                    va = *reinterpret_cast<const ushort8v*>(meanb + (size_t)row * K1 + kg);
                } else {
                    int kr = kg - K1;
                    if (nt0[row] == (kr >> LOG2C))
                        va = *reinterpret_cast<const ushort8v*>(hb + (size_t)row * C + (kr & (C - 1)));
                }
            }
            *reinterpret_cast<ushort8v*>(&ldsA[r * 128 + (skb ^ ((r & 7) << 4))]) = va;
        }
#pragma unroll
        for (int p = 0; p < BN / 32; p++) {
            int r = sr + p * 32;
            int colr = col0 + r;
            ushort8v vb = *reinterpret_cast<const ushort8v*>(Bt + (size_t)colr * K + kg);
            *reinterpret_cast<ushort8v*>(&ldsB[r * 128 + (skb ^ ((r & 7) << 4))]) = vb;
        }
        __syncthreads();
#pragma unroll
        for (int kc = 0; kc < 2; kc++) {
            int kb = kc * 64 + (lane >> 4) * 16;
            bf16x8 af[FM], bfr[FN];
#pragma unroll
            for (int m = 0; m < FM; m++) {
                int r = wrow + m * 16 + (lane & 15);
                af[m] = *reinterpret_cast<const bf16x8*>(&ldsA[r * 128 + (kb ^ ((r & 7) << 4))]);
            }
#pragma unroll
            for (int n = 0; n < FN; n++) {
                int r = wcol + n * 16 + (lane & 15);
                bfr[n] = *reinterpret_cast<const bf16x8*>(&ldsB[r * 128 + (kb ^ ((r & 7) << 4))]);
            }
#pragma unroll
            for (int m = 0; m < FM; m++)
#pragma unroll
                for (int n = 0; n < FN; n++)
                    acc[m][n] = __builtin_amdgcn_mfma_f32_16x16x32_bf16(af[m], bfr[n], acc[m][n], 0, 0, 0);
        }
        __syncthreads();
    }

    // epilogue: C/D mapping col=lane&15, row=(lane>>4)*4+j
#pragma unroll
    for (int m = 0; m < FM; m++) {
        int rbase = row0 + wrow + m * 16 + (lane >> 4) * 4;
#pragma unroll
        for (int n = 0; n < FN; n++) {
            int col = col0 + wcol + n * 16 + (lane & 15);
            if (col >= Nreal) continue;
            f32x4 v = acc[m][n];
#pragma unroll
            for (int j = 0; j < 4; j++) {
                int row = rbase + j;
                if (row >= M) continue;
                float x = v[j] + rootb[nt0[row] * Nreal + col];
                if (RELU) x = fmaxf(x, 0.f);
                if (OUTBF16) outb[(size_t)row * Nreal + col] = f2b(x);
                else         outf[(size_t)row * Nreal + col] = x;
            }
        }
    }
}

// ---------------- in-place log_softmax over rows of N cols ------------------
__global__ void k_logsm(float* __restrict__ out, int M, int N)
{
    int row = blockIdx.x * 4 + (threadIdx.x >> 6);
    if (row >= M) return;
    int lane = threadIdx.x & 63;
    float* p = out + (size_t)row * N;
    float mx = -3.4e38f;
    for (int c = lane; c < N; c += 64) mx = fmaxf(mx, p[c]);
#pragma unroll
    for (int o = 32; o > 0; o >>= 1) mx = fmaxf(mx, __shfl_xor(mx, o));
    float s = 0.f;
    for (int c = lane; c < N; c += 64) s += expf(p[c] - mx);
#pragma unroll
    for (int o = 32; o > 0; o >>= 1) s += __shfl_xor(s, o);
    float lse = mx + logf(s);
    for (int c = lane; c < N; c += 64) p[c] -= lse;
}

extern "C" void kernel_launch(void* const* d_in, const int* in_sizes, int n_in,
                              void* d_out, int out_size, void* d_ws, size_t ws_size,
                              hipStream_t stream)
{
    const int*   n_id   = (const int*)d_in[0];
    const float* x0     = (const float*)d_in[1];
    const int*   src0   = (const int*)d_in[2];
    const int*   dst0   = (const int*)d_in[3];
    const int*   eid0   = (const int*)d_in[4];
    const int*   src1   = (const int*)d_in[5];
    const int*   dst1   = (const int*)d_in[6];
    const int*   eid1   = (const int*)d_in[7];
    const int*   etype  = (const int*)d_in[8];
    const int*   ntype  = (const int*)d_in[9];
    const int*   lidx   = (const int*)d_in[10];
    const float* emb1   = (const float*)d_in[11];
    const float* emb2   = (const float*)d_in[12];
    const float* emb3   = (const float*)d_in[13];
    const float* relW0  = (const float*)d_in[14];
    const float* rootW0 = (const float*)d_in[15];
    const float* rootb0 = (const float*)d_in[16];
    const float* relW1  = (const float*)d_in[17];
    const float* rootW1 = (const float*)d_in[18];
    const float* rootb1 = (const float*)d_in[19];
    float* out = (float*)d_out;

    const int E0 = in_sizes[2];
    const int E1 = in_sizes[5];
    const int Etot = E0 + E1;
    constexpr int K0 = kET * kCIN + kNT * kCIN;   // 1152
    constexpr int Kb1 = kET * kHID + kNT * kHID;  // 2304
    constexpr int Npad1 = 384;

    char* ws = (char*)d_ws;
    size_t off = 0;
    auto alloc = [&](size_t bytes) -> void* {
        void* p = ws + off;
        off = (off + bytes + 255) & ~(size_t)255;
        return p;
    };
    unsigned short* h0b   = (unsigned short*)alloc((size_t)kN0 * kCIN * 2);
    int*            nt0   = (int*)alloc((size_t)kN0 * 4);
    unsigned short* meanb = (unsigned short*)alloc((size_t)kNSEG0 * kCIN * 2); // >= NSEG1*HID
    int*            cnt    = (int*)alloc((size_t)kNSEG * 4);
    int*            starts = (int*)alloc((size_t)kNSEG * 4);
    int*            cnts2d = (int*)alloc((size_t)kNBin * kNBLK * 4);   // ~1 MB
    int*            offs2d = (int*)alloc((size_t)kNBin * kNBLK * 4);   // ~1 MB
    int*            blksum = (int*)alloc(1024 * 4);
    unsigned int*   pairs  = (unsigned int*)alloc((size_t)Etot * 4);   // 7.6 MB
    int*            order  = (int*)alloc((size_t)Etot * 4);            // 7.6 MB
    unsigned short* h1b   = (unsigned short*)alloc((size_t)kN1 * kHID * 2);
    unsigned short* Bt0   = (unsigned short*)alloc((size_t)kHID * K0 * 2);
    unsigned short* Bt1   = (unsigned short*)alloc((size_t)Npad1 * Kb1 * 2);

    // ---- weight prep + input gather (independent of CSR build) ----
    k_prepw<<<(kHID * K0 + 255) / 256, 256, 0, stream>>>(relW0, rootW0, Bt0, kHID, kHID, kET * kCIN, K0);
    k_prepw<<<(Npad1 * Kb1 + 255) / 256, 256, 0, stream>>>(relW1, rootW1, Bt1, kOUT, Npad1, kET * kHID, Kb1);
    k_gather<<<(kN0 + 7) / 8, 256, 0, stream>>>(n_id, x0, emb1, emb2, emb3, ntype, lidx, h0b, nt0);

    // ---- deterministic binned CSR build (no global atomics) ----
    k_bincnt<<<kNBLK, 1024, 0, stream>>>(dst0, eid0, E0, dst1, eid1, E1, etype, cnts2d);
    int nscan = kNBin * kNBLK;
    int nblk = (nscan + 1023) / 1024;
    k_scan1<<<nblk, 1024, 0, stream>>>(cnts2d, offs2d, blksum, nscan);
    k_scan2<<<1, 1024, 0, stream>>>(blksum, nblk);
    k_scan3<<<(nscan + 255) / 256, 256, 0, stream>>>(offs2d, blksum, nscan);
    k_binplace<<<kNBLK, 1024, 0, stream>>>(src0, dst0, eid0, E0, src1, dst1, eid1, E1,
                                           etype, offs2d, pairs);
    k_binscatter<<<kNBin, 1024, 0, stream>>>(offs2d, Etot, pairs, order, starts, cnt);

    // ---- layer 0 ----
    k_segreduce<kCIN><<<(kNSEG0 + 15) / 16, 256, 0, stream>>>(starts, cnt, order, h0b, meanb, kNSEG0);
    dim3 g0((kN1 + 63) / 64, kHID / 128);
    k_gemm_mfma<kCIN, 64, 128, 1, 1><<<g0, 256, 0, stream>>>(kN1, kHID, meanb, h0b, Bt0, rootb0, nt0, h1b, nullptr);

    // ---- layer 1 ----
    k_segreduce<kHID><<<(kNSEG1 + 7) / 8, 256, 0, stream>>>(starts + kNSEG0, cnt + kNSEG0, order, h1b, meanb, kNSEG1);
    dim3 g1((kN2 + 63) / 64, Npad1 / 64);
    k_gemm_mfma<kHID, 64, 64, 0, 0><<<g1, 256, 0, stream>>>(kN2, kOUT, meanb, h1b, Bt1, rootb1, nt0, nullptr, out);

    k_logsm<<<(kN2 + 3) / 4, 256, 0, stream>>>(out, kN2, kOUT);
}